// Round 6
// baseline (368.799 us; speedup 1.0000x reference)
//
#include <hip/hip_runtime.h>

typedef _Float16 f16;
typedef _Float16 f16x8 __attribute__((ext_vector_type(8)));
typedef float f32x4 __attribute__((ext_vector_type(4)));

#define HEADS 32
#define SEQ   2048
#define DIM   64
#define QT    64
#define KT    64
#define NT    32
#define L2E   1.44269504088896340736f

// k -> kf (f16 row-major [h][kv][d]) ; v -> vt (f16 transposed [h][d][kv])
__global__ __launch_bounds__(256) void prep_kernel(const float* __restrict__ k,
                                                   const float* __restrict__ v,
                                                   f16* __restrict__ kf,
                                                   f16* __restrict__ vt) {
  int n = blockIdx.x * 256 + threadIdx.x;
  const int HALF = HEADS * SEQ * (DIM / 8);  // 524288
  if (n < HALF) {
    const float* src = k + (size_t)n * 8;
    float4 a = *(const float4*)src;
    float4 b = *(const float4*)(src + 4);
    f16x8 o;
    o[0]=(f16)a.x; o[1]=(f16)a.y; o[2]=(f16)a.z; o[3]=(f16)a.w;
    o[4]=(f16)b.x; o[5]=(f16)b.y; o[6]=(f16)b.z; o[7]=(f16)b.w;
    *(f16x8*)(kf + (size_t)n * 8) = o;
  } else {
    int m = n - HALF;
    int d   = m & 63;
    int kv8 = ((m >> 6) & 255) * 8;
    int h   = m >> 14;
    const float* src = v + ((size_t)(h * SEQ + kv8)) * DIM + d;
    f16x8 o;
#pragma unroll
    for (int i = 0; i < 8; i++) o[i] = (f16)src[i * DIM];
    *(f16x8*)(vt + ((size_t)(h * DIM + d)) * SEQ + kv8) = o;
  }
}

// QK^T for one 64-kv tile, B-frags direct from L2-resident kf
#define QKT_D(SC, KTILE)                                                               \
  do {                                                                                 \
    _Pragma("unroll") for (int kc = 0; kc < 2; kc++) {                                 \
      _Pragma("unroll") for (int f = 0; f < 4; f++) {                                  \
        f16x8 kb_ = *(const f16x8*)((KTILE) + (f * 16 + c) * 128 + kc * 64 + g * 16);  \
        SC[f] = __builtin_amdgcn_mfma_f32_16x16x32_f16(qa[kc], kb_, SC[f], 0, 0, 0);   \
      }                                                                                \
    }                                                                                  \
  } while (0)

__global__ __launch_bounds__(256, 4) void attn_kernel(const float* __restrict__ q,
                                                      const char* __restrict__ kf,
                                                      const f16* __restrict__ vt,
                                                      float* __restrict__ out_o,
                                                      float* __restrict__ out_p) {
  __shared__ float lds_pt[QT * 64];  // 16 KB fp32 transpose buffer, wave-private rows

  const int tid = threadIdx.x;
  const int w = tid >> 6, l = tid & 63, g = l >> 4, c = l & 15;

  // XCD swizzle: 1024 blocks, 128/XCD -> 4 heads per XCD (K+V = 2 MB, L2-resident)
  const int swz  = (blockIdx.x & 7) * 128 + (blockIdx.x >> 3);
  const int head = swz >> 5;
  const int q0   = (swz & 31) * QT;

  // Q A-fragments (lane c = q-row, g = k-chunk)
  f16x8 qa[2];
  {
    const float* qp = q + ((size_t)(head * SEQ + q0 + w * 16 + c)) * DIM + g * 8;
#pragma unroll
    for (int kc = 0; kc < 2; kc++) {
      float4 a = *(const float4*)(qp + kc * 32);
      float4 b = *(const float4*)(qp + kc * 32 + 4);
      qa[kc][0]=(f16)a.x; qa[kc][1]=(f16)a.y; qa[kc][2]=(f16)a.z; qa[kc][3]=(f16)a.w;
      qa[kc][4]=(f16)b.x; qa[kc][5]=(f16)b.y; qa[kc][6]=(f16)b.z; qa[kc][7]=(f16)b.w;
    }
  }

  const char* khead = kf + (size_t)head * SEQ * 128;
  const f16*  vhead = vt + (size_t)head * DIM * SEQ;

  // ---------------- pass 1: l only (no-max softmax), no barriers ----------------
  float l_ln[4] = {0.f, 0.f, 0.f, 0.f};
  for (int t = 0; t < NT; t++) {
    const char* ktile = khead + (size_t)t * KT * 128;
    f32x4 sc[4];
#pragma unroll
    for (int f = 0; f < 4; f++) sc[f] = (f32x4){0.f, 0.f, 0.f, 0.f};
    QKT_D(sc, ktile);
#pragma unroll
    for (int f = 0; f < 4; f++)
#pragma unroll
      for (int r = 0; r < 4; r++) l_ln[r] += __builtin_amdgcn_exp2f(sc[f][r] * L2E);
  }
  f32x4 rinv;
#pragma unroll
  for (int r = 0; r < 4; r++) {
    float lv = l_ln[r];
#pragma unroll
    for (int d = 1; d < 16; d <<= 1) lv += __shfl_xor(lv, d, 64);
    rinv[r] = 1.0f / lv;
  }

  // ---------------- pass 2: probs stores + PV, no barriers ----------------
  f32x4 o_acc[4];
#pragma unroll
  for (int f = 0; f < 4; f++) o_acc[f] = (f32x4){0.f, 0.f, 0.f, 0.f};
  float* prow = out_p + (size_t)(head * SEQ + q0) * SEQ;

  for (int t = 0; t < NT; t++) {
    const char* ktile = khead + (size_t)t * KT * 128;
    f32x4 sc[4];
#pragma unroll
    for (int f = 0; f < 4; f++) sc[f] = (f32x4){0.f, 0.f, 0.f, 0.f};
    QKT_D(sc, ktile);

    // p = exp2(s*log2e) * rinv -> wave-private swizzled fp32 LDS transpose
#pragma unroll
    for (int f = 0; f < 4; f++)
#pragma unroll
      for (int r = 0; r < 4; r++) {
        float pv = __builtin_amdgcn_exp2f(sc[f][r] * L2E) * rinv[r];
        int rowL = w * 16 + 4 * g + r;
        lds_pt[rowL * 64 + ((16 * f + c) ^ ((rowL & 7) << 2))] = pv;
      }
    asm volatile("" ::: "memory");

    // coalesced probs stores: 4 x f32x4 per lane, 256B contiguous per row, nt
#pragma unroll
    for (int j = 0; j < 4; j++) {
      int rowL = w * 16 + j * 4 + g;
      f32x4 pv4 = *(const f32x4*)&lds_pt[rowL * 64 + ((c ^ (rowL & 7)) << 2)];
      __builtin_nontemporal_store(pv4, (f32x4*)&prow[(size_t)rowL * SEQ + t * 64 + c * 4]);
    }

    // PV: A-frag = own P row from LDS (cvt f16), B-frag = V^T contiguous 16B
    {
      int rowA = w * 16 + c;
      int sw = c & 7;
#pragma unroll
      for (int kc = 0; kc < 2; kc++) {
        f32x4 a0 = *(const f32x4*)&lds_pt[rowA * 64 + (((8 * kc + 2 * g) ^ sw) << 2)];
        f32x4 a1 = *(const f32x4*)&lds_pt[rowA * 64 + (((8 * kc + 2 * g + 1) ^ sw) << 2)];
        f16x8 pa;
        pa[0]=(f16)a0[0]; pa[1]=(f16)a0[1]; pa[2]=(f16)a0[2]; pa[3]=(f16)a0[3];
        pa[4]=(f16)a1[0]; pa[5]=(f16)a1[1]; pa[6]=(f16)a1[2]; pa[7]=(f16)a1[3];
#pragma unroll
        for (int f = 0; f < 4; f++) {
          f16x8 vb = *(const f16x8*)(vhead + (size_t)(f * 16 + c) * SEQ + t * 64 + kc * 32 + g * 8);
          o_acc[f] = __builtin_amdgcn_mfma_f32_16x16x32_f16(pa, vb, o_acc[f], 0, 0, 0);
        }
      }
    }
    asm volatile("" ::: "memory");
  }

  // ---------------- O epilogue: wave-private LDS transpose -> nt stores ----------
#pragma unroll
  for (int f = 0; f < 4; f++)
#pragma unroll
    for (int r = 0; r < 4; r++) {
      int rowL = w * 16 + 4 * g + r;
      lds_pt[rowL * 64 + ((16 * f + c) ^ ((rowL & 7) << 2))] = o_acc[f][r];
    }
  asm volatile("" ::: "memory");
#pragma unroll
  for (int j = 0; j < 4; j++) {
    int rowL = w * 16 + j * 4 + g;
    f32x4 ov = *(const f32x4*)&lds_pt[rowL * 64 + ((c ^ (rowL & 7)) << 2)];
    __builtin_nontemporal_store(ov, (f32x4*)&out_o[(size_t)(head * SEQ + q0 + rowL) * DIM + c * 4]);
  }
}

extern "C" void kernel_launch(void* const* d_in, const int* in_sizes, int n_in,
                              void* d_out, int out_size, void* d_ws, size_t ws_size,
                              hipStream_t stream) {
  const float* k = (const float*)d_in[0];
  const float* q = (const float*)d_in[1];
  const float* v = (const float*)d_in[2];
  float* out_o = (float*)d_out;
  float* out_p = out_o + (size_t)HEADS * SEQ * DIM;

  f16* kf = (f16*)d_ws;                              // 8 MB f16 K row-major
  f16* vt = kf + (size_t)HEADS * SEQ * DIM;          // 8 MB f16 V^T

  prep_kernel<<<dim3(4096), dim3(256), 0, stream>>>(k, v, kf, vt);
  attn_kernel<<<dim3(1024), dim3(256), 0, stream>>>(q, (const char*)kf, vt, out_o, out_p);
}

// Round 7
// 189.243 us; speedup vs baseline: 1.9488x; 1.9488x over previous
//
#include <hip/hip_runtime.h>

typedef _Float16 f16;
typedef _Float16 f16x8 __attribute__((ext_vector_type(8)));
typedef float f32x4 __attribute__((ext_vector_type(4)));

#define HEADS 32
#define SEQ   2048
#define DIM   64
#define QT    64
#define KT    64
#define NT    32
#define L2E   1.44269504088896340736f

__device__ __forceinline__ void gload_lds16(const void* gsrc, void* ldst) {
  __builtin_amdgcn_global_load_lds((__attribute__((address_space(1))) void*)gsrc,
                                   (__attribute__((address_space(3))) void*)ldst, 16, 0, 0);
}

// k -> kt (f16, per-row XOR-swizzled for linear LDS staging)
// v -> vt (f16 transposed [h][d][kv])
__global__ __launch_bounds__(256) void prep_kernel(const float* __restrict__ k,
                                                   const float* __restrict__ v,
                                                   char* __restrict__ kt,
                                                   f16* __restrict__ vt) {
  int n = blockIdx.x * 256 + threadIdx.x;
  const int HALF = HEADS * SEQ * (DIM / 8);  // 524288
  if (n < HALF) {
    int d8 = (n & 7) * 8;
    int kv = (n >> 3) & (SEQ - 1);
    int h  = n >> 14;
    const float* src = k + ((size_t)(h * SEQ + kv)) * DIM + d8;
    float4 a = *(const float4*)src;
    float4 b = *(const float4*)(src + 4);
    f16x8 o;
    o[0]=(f16)a.x; o[1]=(f16)a.y; o[2]=(f16)a.z; o[3]=(f16)a.w;
    o[4]=(f16)b.x; o[5]=(f16)b.y; o[6]=(f16)b.z; o[7]=(f16)b.w;
    *(f16x8*)(kt + ((size_t)(h * SEQ + kv)) * 128 + ((d8 * 2) ^ ((kv & 7) << 4))) = o;
  } else {
    int m = n - HALF;
    int d   = m & 63;
    int kv8 = ((m >> 6) & 255) * 8;
    int h   = m >> 14;
    const float* src = v + ((size_t)(h * SEQ + kv8)) * DIM + d;
    f16x8 o;
#pragma unroll
    for (int i = 0; i < 8; i++) o[i] = (f16)src[i * DIM];
    *(f16x8*)(vt + ((size_t)(h * DIM + d)) * SEQ + kv8) = o;
  }
}

#define STAGE(t, buf)                                                                  \
  do {                                                                                 \
    const char* ktile_ = kthead + (size_t)(t) * KT * 128;                              \
    gload_lds16(ktile_ + tid * 16, &lds_k[buf][tid * 16]);                             \
    gload_lds16(ktile_ + 4096 + tid * 16, &lds_k[buf][4096 + tid * 16]);               \
  } while (0)

#define QKT_M(SC, buf)                                                                 \
  do {                                                                                 \
    _Pragma("unroll") for (int kc = 0; kc < 2; kc++) {                                 \
      _Pragma("unroll") for (int f = 0; f < 4; f++) {                                  \
        int row_ = f * 16 + c;                                                         \
        f16x8 kb_ = *(const f16x8*)&lds_k[buf][row_ * 128 +                            \
                       ((kc * 64 + g * 16) ^ ((row_ & 7) << 4))];                      \
        SC[f] = __builtin_amdgcn_mfma_f32_16x16x32_f16(qa[kc], kb_, SC[f], 0, 0, 0);   \
      }                                                                                \
    }                                                                                  \
  } while (0)

#define LOAD_QA                                                                        \
  do {                                                                                 \
    const float* qp = q + ((size_t)(head * SEQ + q0 + w * 16 + c)) * DIM + g * 8;      \
    _Pragma("unroll") for (int kc = 0; kc < 2; kc++) {                                 \
      float4 a = *(const float4*)(qp + kc * 32);                                       \
      float4 b = *(const float4*)(qp + kc * 32 + 4);                                   \
      qa[kc][0]=(f16)a.x; qa[kc][1]=(f16)a.y; qa[kc][2]=(f16)a.z; qa[kc][3]=(f16)a.w;  \
      qa[kc][4]=(f16)b.x; qa[kc][5]=(f16)b.y; qa[kc][6]=(f16)b.z; qa[kc][7]=(f16)b.w;  \
    }                                                                                  \
  } while (0)

// ============ kernel A: row sums l = sum_k exp(s) (no-max), pure compute ============
__global__ __launch_bounds__(256, 4) void lsum_kernel(const float* __restrict__ q,
                                                      const char* __restrict__ kt,
                                                      float* __restrict__ lsum) {
  __shared__ char lds_k[2][KT * 128];

  const int tid = threadIdx.x;
  const int w = tid >> 6, l = tid & 63, g = l >> 4, c = l & 15;
  const int swz  = (blockIdx.x & 7) * 128 + (blockIdx.x >> 3);
  const int head = swz >> 5;
  const int q0   = (swz & 31) * QT;

  f16x8 qa[2];
  LOAD_QA;
  const char* kthead = kt + (size_t)head * SEQ * 128;

  float l_ln[4] = {0.f, 0.f, 0.f, 0.f};
  STAGE(0, 0);
  __syncthreads();
  for (int t = 0; t < NT; t++) {
    int cur = t & 1;
    if (t + 1 < NT) STAGE(t + 1, cur ^ 1);
    f32x4 sc[4];
#pragma unroll
    for (int f = 0; f < 4; f++) sc[f] = (f32x4){0.f, 0.f, 0.f, 0.f};
    QKT_M(sc, cur);
#pragma unroll
    for (int f = 0; f < 4; f++)
#pragma unroll
      for (int r = 0; r < 4; r++) l_ln[r] += __builtin_amdgcn_exp2f(sc[f][r] * L2E);
    __syncthreads();
  }
#pragma unroll
  for (int r = 0; r < 4; r++) {
    float lv = l_ln[r];
#pragma unroll
    for (int d = 1; d < 16; d <<= 1) lv += __shfl_xor(lv, d, 64);
    if (c == 0) lsum[head * SEQ + q0 + w * 16 + 4 * g + r] = lv;
  }
}

// ============ kernel B: probs stores + PV, writes active from iteration 0 ===========
__global__ __launch_bounds__(256, 4) void attn_kernel(const float* __restrict__ q,
                                                      const char* __restrict__ kt,
                                                      const f16* __restrict__ vt,
                                                      const float* __restrict__ lsum,
                                                      float* __restrict__ out_o,
                                                      float* __restrict__ out_p) {
  __shared__ char  lds_k[2][KT * 128];  // 16 KB K double buffer
  __shared__ float lds_pt[QT * 64];     // 16 KB fp32 transpose buffer (P and O)

  const int tid = threadIdx.x;
  const int w = tid >> 6, l = tid & 63, g = l >> 4, c = l & 15;
  const int swz  = (blockIdx.x & 7) * 128 + (blockIdx.x >> 3);
  const int head = swz >> 5;
  const int q0   = (swz & 31) * QT;

  f16x8 qa[2];
  LOAD_QA;

  const char* kthead = kt + (size_t)head * SEQ * 128;
  const f16*  vhead  = vt + (size_t)head * DIM * SEQ;

  f32x4 rinv;
#pragma unroll
  for (int r = 0; r < 4; r++)
    rinv[r] = 1.0f / lsum[head * SEQ + q0 + w * 16 + 4 * g + r];

  f32x4 o_acc[4];
#pragma unroll
  for (int f = 0; f < 4; f++) o_acc[f] = (f32x4){0.f, 0.f, 0.f, 0.f};
  float* prow = out_p + (size_t)(head * SEQ + q0) * SEQ;

  STAGE(0, 0);
  __syncthreads();
  for (int t = 0; t < NT; t++) {
    int cur = t & 1;
    if (t + 1 < NT) STAGE(t + 1, cur ^ 1);

    // V B-frag register prefetch (L2 latency hides under QKT + exp)
    f16x8 vb[2][4];
#pragma unroll
    for (int kc = 0; kc < 2; kc++)
#pragma unroll
      for (int f = 0; f < 4; f++)
        vb[kc][f] = *(const f16x8*)(vhead + (size_t)(f * 16 + c) * SEQ + t * 64 + kc * 32 + g * 8);

    f32x4 sc[4];
#pragma unroll
    for (int f = 0; f < 4; f++) sc[f] = (f32x4){0.f, 0.f, 0.f, 0.f};
    QKT_M(sc, cur);

    // p = exp2(s*log2e) * rinv -> wave-private swizzled fp32 LDS transpose
#pragma unroll
    for (int f = 0; f < 4; f++)
#pragma unroll
      for (int r = 0; r < 4; r++) {
        float pv = __builtin_amdgcn_exp2f(sc[f][r] * L2E) * rinv[r];
        int rowL = w * 16 + 4 * g + r;
        lds_pt[rowL * 64 + ((16 * f + c) ^ ((rowL & 7) << 2))] = pv;
      }
    asm volatile("" ::: "memory");

    // coalesced probs stores: 4 x f32x4 per lane, 256B contiguous per row, nt
#pragma unroll
    for (int j = 0; j < 4; j++) {
      int rowL = w * 16 + j * 4 + g;
      f32x4 pv4 = *(const f32x4*)&lds_pt[rowL * 64 + ((c ^ (rowL & 7)) << 2)];
      __builtin_nontemporal_store(pv4, (f32x4*)&prow[(size_t)rowL * SEQ + t * 64 + c * 4]);
    }

    // PV: A-frag = own P row from LDS (cvt f16), B-frags already in registers
    {
      int rowA = w * 16 + c;
      int sw = c & 7;
#pragma unroll
      for (int kc = 0; kc < 2; kc++) {
        f32x4 a0 = *(const f32x4*)&lds_pt[rowA * 64 + (((8 * kc + 2 * g) ^ sw) << 2)];
        f32x4 a1 = *(const f32x4*)&lds_pt[rowA * 64 + (((8 * kc + 2 * g + 1) ^ sw) << 2)];
        f16x8 pa;
        pa[0]=(f16)a0[0]; pa[1]=(f16)a0[1]; pa[2]=(f16)a0[2]; pa[3]=(f16)a0[3];
        pa[4]=(f16)a1[0]; pa[5]=(f16)a1[1]; pa[6]=(f16)a1[2]; pa[7]=(f16)a1[3];
#pragma unroll
        for (int f = 0; f < 4; f++)
          o_acc[f] = __builtin_amdgcn_mfma_f32_16x16x32_f16(pa, vb[kc][f], o_acc[f], 0, 0, 0);
      }
    }
    __syncthreads();
  }

  // O epilogue: LDS transpose (wave-private rows) -> coalesced nt stores
#pragma unroll
  for (int f = 0; f < 4; f++)
#pragma unroll
    for (int r = 0; r < 4; r++) {
      int rowL = w * 16 + 4 * g + r;
      lds_pt[rowL * 64 + ((16 * f + c) ^ ((rowL & 7) << 2))] = o_acc[f][r];
    }
  asm volatile("" ::: "memory");
#pragma unroll
  for (int j = 0; j < 4; j++) {
    int rowL = w * 16 + j * 4 + g;
    f32x4 ov = *(const f32x4*)&lds_pt[rowL * 64 + ((c ^ (rowL & 7)) << 2)];
    __builtin_nontemporal_store(ov, (f32x4*)&out_o[(size_t)(head * SEQ + q0 + rowL) * DIM + c * 4]);
  }
}

extern "C" void kernel_launch(void* const* d_in, const int* in_sizes, int n_in,
                              void* d_out, int out_size, void* d_ws, size_t ws_size,
                              hipStream_t stream) {
  const float* k = (const float*)d_in[0];
  const float* q = (const float*)d_in[1];
  const float* v = (const float*)d_in[2];
  float* out_o = (float*)d_out;
  float* out_p = out_o + (size_t)HEADS * SEQ * DIM;

  char*  kt = (char*)d_ws;                                  // 8 MB swizzled f16 K
  f16*   vt = (f16*)(kt + (size_t)HEADS * SEQ * DIM * 2);   // 8 MB f16 V^T
  float* ls = (float*)(vt + (size_t)HEADS * SEQ * DIM);     // 256 KB row sums

  prep_kernel<<<dim3(4096), dim3(256), 0, stream>>>(k, v, kt, vt);
  lsum_kernel<<<dim3(1024), dim3(256), 0, stream>>>(q, kt, ls);
  attn_kernel<<<dim3(1024), dim3(256), 0, stream>>>(q, kt, vt, ls, out_o, out_p);
}